// Round 14
// baseline (161.630 us; speedup 1.0000x reference)
//
#include <hip/hip_runtime.h>
#include <math.h>

// Problem constants
#define NB 32
#define CI 64
#define CO 64
#define CA 16
#define NK 4
#define HH 128
#define WW 128
#define EPSBN 1e-5f

typedef __bf16 bf16x8 __attribute__((ext_vector_type(8)));
typedef float f32x4 __attribute__((ext_vector_type(4)));

__device__ inline unsigned short f2bf(float f) {
    union { float f; unsigned u; } c; c.f = f;
    return (unsigned short)((c.u + 0x7fffu + ((c.u >> 16) & 1u)) >> 16);
}

// packed 2xf32 -> 2xbf16 (lo = first arg), single VALU op
__device__ inline unsigned cvt_pk_bf16(float lo, float hi) {
    unsigned r;
    asm("v_cvt_pk_bf16_f32 %0, %1, %2" : "=v"(r) : "v"(lo), "v"(hi));
    return r;
}

__device__ inline void gload_lds16(const void* g, void* l) {
    __builtin_amdgcn_global_load_lds(
        (const __attribute__((address_space(1))) unsigned int*)g,
        (__attribute__((address_space(3))) unsigned int*)l, 16, 0, 0);
}

// Workspace layout (float offsets). Total 70.5 MB (proven available).
#define WS_ZERO  0              // 64 (zero page for OOB redirect)
#define WS_CHA   64             // 2048
#define WS_FA    2112           // 2048
#define WS_KA    4160           // 128
#define WS_SP    4288           // 288
#define WS_PART  8192           // 32*64*128 = 262144
#define WS_W2T   270336         // 1179648 ushorts
#define WS_XT    860160         // 33554432 ushorts

// ===========================================================================
// 1) transpose + pool, sector-dense BOTH sides. Block = (h, b), 256 thr.
//    Read: thread (w4 = tid&31, ci8 = tid>>5): 8 float4 from 8 planes
//    (per wave instr: 2 planes x 512B dense). Pool fused via shfl_xor.
//    Then pack bf16 -> LDS [w 128][slot 8][16B] with slot = ci8 ^ (w4&7)
//    (<=4-way writes) -> barrier -> thread (w = tid>>1, half = tid&1) reads
//    its 4 slots and stores 64B contiguous per lane: addr = tid*64 + k*16,
//    i.e. every store instruction is 1KB fully dense.
// ===========================================================================
__global__ __launch_bounds__(256, 4) void transpose_pool(const float* __restrict__ x,
                                                         unsigned short* __restrict__ xt,
                                                         float* __restrict__ partial,
                                                         float* __restrict__ zeros) {
    __shared__ __align__(16) unsigned char tl[128 * 128];   // 16 KB
    const int tid = threadIdx.x;
    const int h = blockIdx.x;
    const int b = blockIdx.y;
    const int w4  = tid & 31;
    const int ci8 = tid >> 5;        // 0..7 (8 ci each)

    if (h == 0 && b == 0 && tid < 64) zeros[tid] = 0.f;   // zero page for conv

    float4 v[8];
    const float* xp = x + ((size_t)(b * CI + ci8 * 8) * HH + h) * WW + w4 * 4;
    #pragma unroll
    for (int i = 0; i < 8; ++i) v[i] = *(const float4*)(xp + (size_t)i * (HH * WW));

    // fused pool: sum over this thread's 4 w, reduce over the 32 w4 lanes
    float s8[8];
    #pragma unroll
    for (int i = 0; i < 8; ++i) s8[i] = v[i].x + v[i].y + v[i].z + v[i].w;
    #pragma unroll
    for (int mask = 1; mask <= 16; mask <<= 1)
        #pragma unroll
        for (int i = 0; i < 8; ++i) s8[i] += __shfl_xor(s8[i], mask, 64);
    if (w4 == 0) {
        #pragma unroll
        for (int j = 0; j < 8; ++j)
            partial[((size_t)b * CI + ci8 * 8 + j) * HH + h] = s8[j];
    }

    // pack + LDS write (slot-swizzled)
    const int slot = ci8 ^ (w4 & 7);         // (w>>2)&7 == w4&7 for w = w4*4+e
    #pragma unroll
    for (int e = 0; e < 4; ++e) {
        float ve[8];
        #pragma unroll
        for (int i = 0; i < 8; ++i)
            ve[i] = (e == 0) ? v[i].x : (e == 1) ? v[i].y : (e == 2) ? v[i].z : v[i].w;
        unsigned q[4];
        #pragma unroll
        for (int j = 0; j < 4; ++j) q[j] = cvt_pk_bf16(ve[2 * j], ve[2 * j + 1]);
        *(uint4*)(tl + (w4 * 4 + e) * 128 + (slot << 4)) = make_uint4(q[0], q[1], q[2], q[3]);
    }
    __syncthreads();

    // dense store: thread (w, half) -> 64B contiguous
    const int w = tid >> 1, half = tid & 1;
    uint4 r[4];
    #pragma unroll
    for (int k = 0; k < 4; ++k) {
        const int sl = (half * 4 + k) ^ ((w >> 2) & 7);
        r[k] = *(const uint4*)(tl + w * 128 + (sl << 4));
    }
    unsigned short* dst = xt + ((size_t)(b * HH + h) * WW + w) * CI + half * 32;
    #pragma unroll
    for (int k = 0; k < 4; ++k) ((uint4*)dst)[k] = r[k];
}

// ===========================================================================
// 2) attention: reduce partials (128 h, contiguous) + trunk + 4 heads.
// ===========================================================================
__global__ __launch_bounds__(512) void attn3(
    const float* __restrict__ partial, const float* __restrict__ prep_w,
    const float* __restrict__ bn_g, const float* __restrict__ bn_b,
    const float* __restrict__ bn_m, const float* __restrict__ bn_v,
    const float* __restrict__ fc_sp_w, const float* __restrict__ fc_sp_b,
    const float* __restrict__ fc_ch_w, const float* __restrict__ fc_ch_b,
    const float* __restrict__ fc_f_w,  const float* __restrict__ fc_f_b,
    const float* __restrict__ fc_k_w,  const float* __restrict__ fc_k_b,
    float* __restrict__ sp, float* __restrict__ cha,
    float* __restrict__ fa, float* __restrict__ ka) {
    __shared__ float pooled_s[NB * CI];
    __shared__ float att_s[NB * CA];
    const int tid = threadIdx.x;
    const float scale = 1.f / (HH * WW);
    #pragma unroll
    for (int i = 0; i < 4; ++i) {
        const int e = tid + 512 * i;
        const float4* pp = (const float4*)(partial + (size_t)e * HH);
        float s = 0.f;
        #pragma unroll
        for (int j = 0; j < 32; ++j) { float4 v = pp[j]; s += v.x + v.y + v.z + v.w; }
        pooled_s[e] = s;
    }
    __syncthreads();
    const int b = tid >> 4, a = tid & 15;
    {
        float s = 0.f;
        const float* pv = pooled_s + b * CI;
        #pragma unroll
        for (int c = 0; c < CI; ++c) s += pv[c] * prep_w[a * CI + c];
        s = (s * scale - bn_m[a]) * rsqrtf(bn_v[a] + EPSBN) * bn_g[a] + bn_b[a];
        att_s[b * CA + a] = fmaxf(s, 0.f);
    }
    __syncthreads();
    float av[CA];
    #pragma unroll
    for (int i = 0; i < CA; ++i) av[i] = att_s[b * CA + i];

    const int j = a;
    if (j < 9) {
        float s = fc_sp_b[j];
        #pragma unroll
        for (int i = 0; i < CA; ++i) s += av[i] * fc_sp_w[j * CA + i];
        sp[b * 9 + j] = 1.f / (1.f + expf(-s));
    }
    #pragma unroll
    for (int t = 0; t < 4; ++t) {
        const int c = j * 4 + t;
        float s1 = fc_ch_b[c], s2 = fc_f_b[c];
        #pragma unroll
        for (int i = 0; i < CA; ++i) {
            s1 += av[i] * fc_ch_w[c * CA + i];
            s2 += av[i] * fc_f_w[c * CA + i];
        }
        cha[b * CI + c] = 1.f / (1.f + expf(-s1));
        fa[b * CO + c]  = 1.f / (1.f + expf(-s2));
    }
    if (j == 0) {
        float kv[NK], m = -1e30f;
        #pragma unroll
        for (int k = 0; k < NK; ++k) {
            float s = fc_k_b[k];
            #pragma unroll
            for (int i = 0; i < CA; ++i) s += av[i] * fc_k_w[k * CA + i];
            kv[k] = s; m = fmaxf(m, s);
        }
        float den = 0.f;
        #pragma unroll
        for (int k = 0; k < NK; ++k) { kv[k] = expf(kv[k] - m); den += kv[k]; }
        #pragma unroll
        for (int k = 0; k < NK; ++k) ka[b * NK + k] = kv[k] / den;
    }
}

// ===========================================================================
// 3) folded weights w2t[b][tap][o][i] bf16 (lanes = i: 128B-line writes)
// ===========================================================================
__global__ __launch_bounds__(256) void w2t2(const float* __restrict__ kernels,
                                            const float* __restrict__ sp,
                                            const float* __restrict__ cha,
                                            const float* __restrict__ fa,
                                            const float* __restrict__ ka,
                                            unsigned short* __restrict__ w2t) {
    const int bid = blockIdx.x;              // 32*16
    const int b  = bid >> 4;
    const int o  = (bid & 15) * 4 + (threadIdx.x >> 6);
    const int i  = threadIdx.x & 63;
    float kw[NK][9];
    #pragma unroll
    for (int k = 0; k < NK; ++k) {
        const float* kp = kernels + ((size_t)(k * CO + o) * CI + i) * 9;
        #pragma unroll
        for (int t = 0; t < 9; ++t) kw[k][t] = kp[t];
    }
    float kav[NK];
    #pragma unroll
    for (int k = 0; k < NK; ++k) kav[k] = ka[b * NK + k];
    const float base = cha[b * CI + i] * fa[b * CO + o];
    #pragma unroll
    for (int tap = 0; tap < 9; ++tap) {
        float s = 0.f;
        #pragma unroll
        for (int k = 0; k < NK; ++k) s += kav[k] * kw[k][tap];
        w2t[((size_t)(b * 9 + tap) * CO + o) * CI + i] = f2bf(s * sp[b * 9 + tap] * base);
    }
}

// ===========================================================================
// 4) conv (mfma_f32_16x16x32_bf16): dense gload_lds x-stage from xt (r9) +
//    phase-pipelined A double-buffer (r13). Block = 64co x 32col x 4row,
//    256 thr / 4 waves (cohalf x colh). LDS 51200B = x-tile 26624 (oct-XOR
//    layout, zero conflicts measured) + A dbuf 2 x 12288.
// ===========================================================================
#define ABASE 26624
#define ABUFB 12288

__global__ __launch_bounds__(256, 3) void conv_lds(const unsigned short* __restrict__ xt,
                                                   const unsigned short* __restrict__ w2t,
                                                   const unsigned short* __restrict__ zeros,
                                                   float* __restrict__ out) {
    __shared__ __align__(16) unsigned char xs[ABASE + 2 * ABUFB];   // 51200
    const int tid  = threadIdx.x;
    const int lane = tid & 63;
    const int wv   = tid >> 6;
    const int orig = blockIdx.x;
    const int bid  = (orig & 7) * 512 + (orig >> 3);    // XCD swizzle (4096 = 8*512)
    const int b    = bid >> 7;
    const int rem  = bid & 127;
    const int colg = rem & 3;
    const int hg   = rem >> 2;
    const int h0 = hg * 4;
    const int w0 = colg * 32;

    const unsigned short* xb = xt + (size_t)b * (HH * WW * CI);
    const unsigned short* w2base = w2t + (size_t)b * 36864;

    // A chunk stager: chunk c = (ks = c/3, v = c%3) -> buf (c&1).
    // 12 units: u = ch>>2, q = ch&3; lanes = o. dest [u][q(kq)][o].
    auto stageA = [&](int c) {
        const int ks = c / 3, v = c - ks * 3;
        unsigned char* abuf = xs + ABASE + (c & 1) * ABUFB;
        for (int ch = wv; ch < 12; ch += 4) {
            const int u  = ch >> 2;
            const int q  = ch & 3;
            const unsigned short* g = w2base + (size_t)(u * 3 + v) * 4096
                                    + lane * 64 + ks * 32 + q * 8;
            gload_lds16(g, abuf + (ch << 10));
        }
    };

    // ---- x-stage: 6r x 34c x 8oct = 1632 dense 16B units (26 chunks)
    for (int chunk = wv; chunk < 26; chunk += 4) {
        const int unit = (chunk << 6) + lane;
        const int row  = (int)((unsigned)unit / 272u);
        const int rr   = unit - row * 272;
        const int col  = rr >> 3;
        const int q    = rr & 7;
        const int hh = h0 - 1 + row;
        const int wc = w0 - 1 + col;
        const unsigned short* g = zeros;
        if (unit < 1632 && (unsigned)hh < (unsigned)HH && (unsigned)wc < (unsigned)WW)
            g = xb + (((size_t)hh << 7) + (size_t)wc) * 64 + ((q ^ (col & 7)) << 3);
        gload_lds16(g, xs + (chunk << 10));
    }
    // A chunk 0 in flight too
    stageA(0);
    __syncthreads();

    const int cl = lane & 15;        // pixel col in 16 / o in 16
    const int kq = lane >> 4;        // k-quarter within ks-half (8 ci)
    const int cohalf = wv & 1;
    const int colh   = wv >> 1;      // 0..1

    f32x4 acc[2][4];
    #pragma unroll
    for (int og = 0; og < 2; ++og)
        #pragma unroll
        for (int t = 0; t < 4; ++t)
            #pragma unroll
            for (int e = 0; e < 4; ++e) acc[og][t][e] = 0.f;

    const int lcol0 = colh * 16 + cl;
    const int aoff  = kq * 1024 + (cohalf * 32 + cl) * 16;

    // ---- 6 phases: compute chunk c while chunk c+1 streams in
    #pragma unroll
    for (int c = 0; c < 6; ++c) {
        const int ks = c / 3, v = c - ks * 3;
        if (c < 5) stageA(c + 1);
        const unsigned char* abuf = xs + ABASE + (c & 1) * ABUFB;
        const int lcol = lcol0 + v;
        const int sw = ((ks << 2) + kq) ^ (lcol & 7);
        const unsigned char* bp = xs + (((lcol << 3) + sw) << 4);
        bf16x8 Bf[6];
        #pragma unroll
        for (int r = 0; r < 6; ++r) Bf[r] = *(const bf16x8*)(bp + r * 4352);
        #pragma unroll
        for (int u = 0; u < 3; ++u) {
            const unsigned char* ap = abuf + u * 4096 + aoff;
            const bf16x8 A0 = *(const bf16x8*)(ap);
            const bf16x8 A1 = *(const bf16x8*)(ap + 256);     // og=1: +16 o
            #pragma unroll
            for (int t = 0; t < 4; ++t)
                acc[0][t] = __builtin_amdgcn_mfma_f32_16x16x32_bf16(A0, Bf[t + u], acc[0][t], 0, 0, 0);
            #pragma unroll
            for (int t = 0; t < 4; ++t)
                acc[1][t] = __builtin_amdgcn_mfma_f32_16x16x32_bf16(A1, Bf[t + u], acc[1][t], 0, 0, 0);
        }
        __syncthreads();
    }

    // ---- epilogue: o = cohalf*32 + og*16 + kq*4 + rg, col = w0 + colh*16 + cl
    #pragma unroll
    for (int og = 0; og < 2; ++og)
        #pragma unroll
        for (int t = 0; t < 4; ++t) {
            float* op = out + ((size_t)(b * CO + cohalf * 32 + og * 16 + kq * 4) * HH + h0 + t) * WW
                      + w0 + colh * 16 + cl;
            #pragma unroll
            for (int rg = 0; rg < 4; ++rg)
                op[(size_t)rg * (HH * WW)] = acc[og][t][rg];
        }
}

// ===========================================================================
extern "C" void kernel_launch(void* const* d_in, const int* in_sizes, int n_in,
                              void* d_out, int out_size, void* d_ws, size_t ws_size,
                              hipStream_t stream) {
    const float* x        = (const float*)d_in[0];
    const float* prep_w   = (const float*)d_in[1];
    const float* bn_g     = (const float*)d_in[2];
    const float* bn_b     = (const float*)d_in[3];
    const float* bn_m     = (const float*)d_in[4];
    const float* bn_v     = (const float*)d_in[5];
    const float* fc_sp_w  = (const float*)d_in[6];
    const float* fc_sp_b  = (const float*)d_in[7];
    const float* fc_ch_w  = (const float*)d_in[8];
    const float* fc_ch_b  = (const float*)d_in[9];
    const float* fc_f_w   = (const float*)d_in[10];
    const float* fc_f_b   = (const float*)d_in[11];
    const float* fc_k_w   = (const float*)d_in[12];
    const float* fc_k_b   = (const float*)d_in[13];
    const float* kernels  = (const float*)d_in[14];
    float* out = (float*)d_out;
    float* ws  = (float*)d_ws;

    float* zeros   = ws + WS_ZERO;
    float* cha     = ws + WS_CHA;
    float* fa      = ws + WS_FA;
    float* ka      = ws + WS_KA;
    float* sp      = ws + WS_SP;
    float* partial = ws + WS_PART;
    unsigned short* w2t = (unsigned short*)(ws + WS_W2T);
    unsigned short* xt  = (unsigned short*)(ws + WS_XT);

    transpose_pool<<<dim3(HH, NB), 256, 0, stream>>>(x, xt, partial, zeros);
    attn3<<<1, 512, 0, stream>>>(partial, prep_w, bn_g, bn_b, bn_m, bn_v,
                                 fc_sp_w, fc_sp_b, fc_ch_w, fc_ch_b,
                                 fc_f_w, fc_f_b, fc_k_w, fc_k_b,
                                 sp, cha, fa, ka);
    w2t2<<<NB * 16, 256, 0, stream>>>(kernels, sp, cha, fa, ka, w2t);
    conv_lds<<<4096, 256, 0, stream>>>(xt, w2t, (const unsigned short*)zeros, out);
}

// Round 15
// 124.507 us; speedup vs baseline: 1.2982x; 1.2982x over previous
//
#include <hip/hip_runtime.h>
#include <math.h>

// Problem constants
#define NB 32
#define CI 64
#define CO 64
#define CA 16
#define NK 4
#define HH 128
#define WW 128
#define EPSBN 1e-5f

typedef __bf16 bf16x8 __attribute__((ext_vector_type(8)));
typedef float f32x4 __attribute__((ext_vector_type(4)));

__device__ inline unsigned short f2bf(float f) {
    union { float f; unsigned u; } c; c.f = f;
    return (unsigned short)((c.u + 0x7fffu + ((c.u >> 16) & 1u)) >> 16);
}

// packed 2xf32 -> 2xbf16 (lo = first arg), single VALU op
__device__ inline unsigned cvt_pk_bf16(float lo, float hi) {
    unsigned r;
    asm("v_cvt_pk_bf16_f32 %0, %1, %2" : "=v"(r) : "v"(lo), "v"(hi));
    return r;
}

__device__ inline void gload_lds16(const void* g, void* l) {
    __builtin_amdgcn_global_load_lds(
        (const __attribute__((address_space(1))) unsigned int*)g,
        (__attribute__((address_space(3))) unsigned int*)l, 16, 0, 0);
}

// Workspace layout (float offsets). ~2.4 MB total.
#define WS_POOLED 0             // 2048
#define WS_CHA    2048          // 2048
#define WS_FA     4096          // 2048
#define WS_KA     6144          // 128
#define WS_SP     6272          // 288
#define WS_W2T    8192          // 1179648 ushorts

// ===========================================================================
// 1) pool: pure streaming reduce. Block = (b,ci) plane (64KB contiguous).
// ===========================================================================
__global__ __launch_bounds__(256, 4) void pool_kernel(const float* __restrict__ x,
                                                      float* __restrict__ pooled) {
    const int plane = blockIdx.x;               // 2048
    const float4* p = (const float4*)(x + (size_t)plane * (HH * WW));
    float4 v[16];
    #pragma unroll
    for (int i = 0; i < 16; ++i) v[i] = p[threadIdx.x + 256 * i];
    float s = 0.f;
    #pragma unroll
    for (int i = 0; i < 16; ++i) s += v[i].x + v[i].y + v[i].z + v[i].w;
    #pragma unroll
    for (int off = 32; off > 0; off >>= 1) s += __shfl_down(s, off);
    __shared__ float red[4];
    if ((threadIdx.x & 63) == 0) red[threadIdx.x >> 6] = s;
    __syncthreads();
    if (threadIdx.x == 0)
        pooled[plane] = red[0] + red[1] + red[2] + red[3];   // sum; scaled in attn
}

// ===========================================================================
// 2) attention: trunk + 4 heads from pooled sums. 1 block, 512 thr.
// ===========================================================================
__global__ __launch_bounds__(512) void attn3(
    const float* __restrict__ pooled, const float* __restrict__ prep_w,
    const float* __restrict__ bn_g, const float* __restrict__ bn_b,
    const float* __restrict__ bn_m, const float* __restrict__ bn_v,
    const float* __restrict__ fc_sp_w, const float* __restrict__ fc_sp_b,
    const float* __restrict__ fc_ch_w, const float* __restrict__ fc_ch_b,
    const float* __restrict__ fc_f_w,  const float* __restrict__ fc_f_b,
    const float* __restrict__ fc_k_w,  const float* __restrict__ fc_k_b,
    float* __restrict__ sp, float* __restrict__ cha,
    float* __restrict__ fa, float* __restrict__ ka) {
    __shared__ float pooled_s[NB * CI];
    __shared__ float att_s[NB * CA];
    const int tid = threadIdx.x;
    const float scale = 1.f / (HH * WW);
    #pragma unroll
    for (int i = 0; i < 4; ++i) {
        const int e = tid + 512 * i;
        pooled_s[e] = pooled[e];
    }
    __syncthreads();
    const int b = tid >> 4, a = tid & 15;
    {
        float s = 0.f;
        const float* pv = pooled_s + b * CI;
        #pragma unroll
        for (int c = 0; c < CI; ++c) s += pv[c] * prep_w[a * CI + c];
        s = (s * scale - bn_m[a]) * rsqrtf(bn_v[a] + EPSBN) * bn_g[a] + bn_b[a];
        att_s[b * CA + a] = fmaxf(s, 0.f);
    }
    __syncthreads();
    float av[CA];
    #pragma unroll
    for (int i = 0; i < CA; ++i) av[i] = att_s[b * CA + i];

    const int j = a;
    if (j < 9) {
        float s = fc_sp_b[j];
        #pragma unroll
        for (int i = 0; i < CA; ++i) s += av[i] * fc_sp_w[j * CA + i];
        sp[b * 9 + j] = 1.f / (1.f + expf(-s));
    }
    #pragma unroll
    for (int t = 0; t < 4; ++t) {
        const int c = j * 4 + t;
        float s1 = fc_ch_b[c], s2 = fc_f_b[c];
        #pragma unroll
        for (int i = 0; i < CA; ++i) {
            s1 += av[i] * fc_ch_w[c * CA + i];
            s2 += av[i] * fc_f_w[c * CA + i];
        }
        cha[b * CI + c] = 1.f / (1.f + expf(-s1));
        fa[b * CO + c]  = 1.f / (1.f + expf(-s2));
    }
    if (j == 0) {
        float kv[NK], m = -1e30f;
        #pragma unroll
        for (int k = 0; k < NK; ++k) {
            float s = fc_k_b[k];
            #pragma unroll
            for (int i = 0; i < CA; ++i) s += av[i] * fc_k_w[k * CA + i];
            kv[k] = s; m = fmaxf(m, s);
        }
        float den = 0.f;
        #pragma unroll
        for (int k = 0; k < NK; ++k) { kv[k] = expf(kv[k] - m); den += kv[k]; }
        #pragma unroll
        for (int k = 0; k < NK; ++k) ka[b * NK + k] = kv[k] / den;
    }
}

// ===========================================================================
// 3) folded weights w2t[b][tap][o][i] bf16 (lanes = i: 128B-line writes)
// ===========================================================================
__global__ __launch_bounds__(256) void w2t2(const float* __restrict__ kernels,
                                            const float* __restrict__ sp,
                                            const float* __restrict__ cha,
                                            const float* __restrict__ fa,
                                            const float* __restrict__ ka,
                                            unsigned short* __restrict__ w2t) {
    const int bid = blockIdx.x;              // 32*16
    const int b  = bid >> 4;
    const int o  = (bid & 15) * 4 + (threadIdx.x >> 6);
    const int i  = threadIdx.x & 63;
    float kw[NK][9];
    #pragma unroll
    for (int k = 0; k < NK; ++k) {
        const float* kp = kernels + ((size_t)(k * CO + o) * CI + i) * 9;
        #pragma unroll
        for (int t = 0; t < 9; ++t) kw[k][t] = kp[t];
    }
    float kav[NK];
    #pragma unroll
    for (int k = 0; k < NK; ++k) kav[k] = ka[b * NK + k];
    const float base = cha[b * CI + i] * fa[b * CO + o];
    #pragma unroll
    for (int tap = 0; tap < 9; ++tap) {
        float s = 0.f;
        #pragma unroll
        for (int k = 0; k < NK; ++k) s += kav[k] * kw[k][tap];
        w2t[((size_t)(b * 9 + tap) * CO + o) * CI + i] = f2bf(s * sp[b * 9 + tap] * base);
    }
}

// ===========================================================================
// 4) FUSED conv (mfma_f32_16x16x32_bf16): reads x f32 NCHW directly with
//    DENSE-LANE staging. Block = 64co x 32col x 4row, 256 thr / 4 waves.
//    x-stage: lane = (strand g = lane>>2) x (seg qlane = lane&3): each wave
//    instruction covers 16 strands x 64B ALIGNED groups (16 merged requests
//    vs 64 scattered). Thread loads the even-ci AND odd-ci strand of the
//    same (row, col-window) -> cvt_pk -> 4 ds_write_b32 (2-way banks, free).
//    LDS tile layout byte-identical to r12-proven B-read pattern.
//    A: phase-pipelined double buffer (r13-proven): 6 chunks of (ks, v),
//    chunk c+1 streamed via gload_lds during compute of chunk c.
//    LDS 51200B = x 26624 + A dbuf 2 x 12288. 3 blocks/CU.
// ===========================================================================
#define ABASE 26624
#define ABUFB 12288

__global__ __launch_bounds__(256, 3) void conv_fused(const float* __restrict__ x,
                                                     const unsigned short* __restrict__ w2t,
                                                     float* __restrict__ out) {
    __shared__ __align__(16) unsigned char xs[ABASE + 2 * ABUFB];   // 51200
    const int tid  = threadIdx.x;
    const int lane = tid & 63;
    const int wv   = tid >> 6;
    const int orig = blockIdx.x;
    const int bid  = (orig & 7) * 512 + (orig >> 3);    // XCD swizzle (4096 = 8*512)
    const int b    = bid >> 7;
    const int rem  = bid & 127;
    const int colg = rem & 3;
    const int hg   = rem >> 2;
    const int h0 = hg * 4;
    const int w0 = colg * 32;

    const unsigned short* w2base = w2t + (size_t)b * 36864;

    // A chunk stager: chunk c = (ks = c/3, v = c%3) -> buf (c&1).
    auto stageA = [&](int c) {
        const int ks = c / 3, v = c - ks * 3;
        unsigned char* abuf = xs + ABASE + (c & 1) * ABUFB;
        for (int ch = wv; ch < 12; ch += 4) {
            const int u  = ch >> 2;
            const int q  = ch & 3;
            const unsigned short* g = w2base + (size_t)(u * 3 + v) * 4096
                                    + lane * 64 + ks * 32 + q * 8;
            gload_lds16(g, abuf + (ch << 10));
        }
    };

    // A chunk 0 issued first (deepest latency, overlaps x staging)
    stageA(0);

    // ---- x-stage, dense-lane mapping.
    //      pair-strand P = (row*3 + iq)*32 + cip; wave does 9 iterations of
    //      16 pair-strands; lane = (g = strand-in-16) x (qlane = f4-seg).
    {
        const int qlane = lane & 3;
        const int g     = lane >> 2;
        #pragma unroll
        for (int it = 0; it < 9; ++it) {
            const int base = (wv * 9 + it) * 16;     // multiple of 16
            const int blk  = base >> 5;              // row*3 + iq
            const int row  = blk / 3;
            const int iq   = blk - row * 3;
            const int cip  = (base & 31) + g;        // 16 consecutive ci-pairs
            const int hh   = h0 - 1 + row;
            const int cg   = w0 - 8 + iq * 16 + qlane * 4;   // f4 col start (64B-aligned groups)
            const bool ok  = ((unsigned)hh < (unsigned)HH) && ((unsigned)cg <= 124u);
            float4 a  = make_float4(0.f, 0.f, 0.f, 0.f);
            float4 c4 = make_float4(0.f, 0.f, 0.f, 0.f);
            if (ok) {
                const float* p0 = x + ((size_t)(b * CI + 2 * cip) * HH + hh) * WW + cg;
                a  = *(const float4*)p0;
                c4 = *(const float4*)(p0 + HH * WW);
            }
            unsigned char* rbase = xs + row * 4352;
            const int oct = cip >> 2, lo = (cip & 3) * 4;
            const float av[4] = {a.x, a.y, a.z, a.w};
            const float cv[4] = {c4.x, c4.y, c4.z, c4.w};
            #pragma unroll
            for (int e = 0; e < 4; ++e) {
                const int cl_ = iq * 16 + qlane * 4 + e - 7;
                if ((unsigned)cl_ < 34u) {
                    *(unsigned*)(rbase + cl_ * 128 + ((oct ^ (cl_ & 7)) << 4) + lo) =
                        cvt_pk_bf16(av[e], cv[e]);
                }
            }
        }
    }
    __syncthreads();

    const int cl = lane & 15;        // pixel col in 16 / o in 16
    const int kq = lane >> 4;        // k-quarter within ks-half (8 ci)
    const int cohalf = wv & 1;
    const int colh   = wv >> 1;      // 0..1

    f32x4 acc[2][4];
    #pragma unroll
    for (int og = 0; og < 2; ++og)
        #pragma unroll
        for (int t = 0; t < 4; ++t)
            #pragma unroll
            for (int e = 0; e < 4; ++e) acc[og][t][e] = 0.f;

    const int lcol0 = colh * 16 + cl;
    const int aoff  = kq * 1024 + (cohalf * 32 + cl) * 16;

    // ---- 6 phases: compute chunk c while chunk c+1 streams in
    #pragma unroll
    for (int c = 0; c < 6; ++c) {
        const int ks = c / 3, v = c - ks * 3;
        if (c < 5) stageA(c + 1);
        const unsigned char* abuf = xs + ABASE + (c & 1) * ABUFB;
        const int lcol = lcol0 + v;
        const int sw = ((ks << 2) + kq) ^ (lcol & 7);
        const unsigned char* bp = xs + (((lcol << 3) + sw) << 4);
        bf16x8 Bf[6];
        #pragma unroll
        for (int r = 0; r < 6; ++r) Bf[r] = *(const bf16x8*)(bp + r * 4352);
        #pragma unroll
        for (int u = 0; u < 3; ++u) {
            const unsigned char* ap = abuf + u * 4096 + aoff;
            const bf16x8 A0 = *(const bf16x8*)(ap);
            const bf16x8 A1 = *(const bf16x8*)(ap + 256);     // og=1: +16 o
            #pragma unroll
            for (int t = 0; t < 4; ++t)
                acc[0][t] = __builtin_amdgcn_mfma_f32_16x16x32_bf16(A0, Bf[t + u], acc[0][t], 0, 0, 0);
            #pragma unroll
            for (int t = 0; t < 4; ++t)
                acc[1][t] = __builtin_amdgcn_mfma_f32_16x16x32_bf16(A1, Bf[t + u], acc[1][t], 0, 0, 0);
        }
        __syncthreads();
    }

    // ---- epilogue: o = cohalf*32 + og*16 + kq*4 + rg, col = w0 + colh*16 + cl
    #pragma unroll
    for (int og = 0; og < 2; ++og)
        #pragma unroll
        for (int t = 0; t < 4; ++t) {
            float* op = out + ((size_t)(b * CO + cohalf * 32 + og * 16 + kq * 4) * HH + h0 + t) * WW
                      + w0 + colh * 16 + cl;
            #pragma unroll
            for (int rg = 0; rg < 4; ++rg)
                op[(size_t)rg * (HH * WW)] = acc[og][t][rg];
        }
}

// ===========================================================================
extern "C" void kernel_launch(void* const* d_in, const int* in_sizes, int n_in,
                              void* d_out, int out_size, void* d_ws, size_t ws_size,
                              hipStream_t stream) {
    const float* x        = (const float*)d_in[0];
    const float* prep_w   = (const float*)d_in[1];
    const float* bn_g     = (const float*)d_in[2];
    const float* bn_b     = (const float*)d_in[3];
    const float* bn_m     = (const float*)d_in[4];
    const float* bn_v     = (const float*)d_in[5];
    const float* fc_sp_w  = (const float*)d_in[6];
    const float* fc_sp_b  = (const float*)d_in[7];
    const float* fc_ch_w  = (const float*)d_in[8];
    const float* fc_ch_b  = (const float*)d_in[9];
    const float* fc_f_w   = (const float*)d_in[10];
    const float* fc_f_b   = (const float*)d_in[11];
    const float* fc_k_w   = (const float*)d_in[12];
    const float* fc_k_b   = (const float*)d_in[13];
    const float* kernels  = (const float*)d_in[14];
    float* out = (float*)d_out;
    float* ws  = (float*)d_ws;

    float* pooled = ws + WS_POOLED;
    float* cha    = ws + WS_CHA;
    float* fa     = ws + WS_FA;
    float* ka     = ws + WS_KA;
    float* sp     = ws + WS_SP;
    unsigned short* w2t = (unsigned short*)(ws + WS_W2T);

    pool_kernel<<<NB * CI, 256, 0, stream>>>(x, pooled);
    attn3<<<1, 512, 0, stream>>>(pooled, prep_w, bn_g, bn_b, bn_m, bn_v,
                                 fc_sp_w, fc_sp_b, fc_ch_w, fc_ch_b,
                                 fc_f_w, fc_f_b, fc_k_w, fc_k_b,
                                 sp, cha, fa, ka);
    w2t2<<<NB * 16, 256, 0, stream>>>(kernels, sp, cha, fa, ka, w2t);
    conv_fused<<<4096, 256, 0, stream>>>(x, w2t, out);
}

// Round 16
// 116.857 us; speedup vs baseline: 1.3831x; 1.0655x over previous
//
#include <hip/hip_runtime.h>
#include <math.h>

// Problem constants
#define NB 32
#define CI 64
#define CO 64
#define CA 16
#define NK 4
#define HH 128
#define WW 128
#define EPSBN 1e-5f

typedef __bf16 bf16x8 __attribute__((ext_vector_type(8)));
typedef float f32x4 __attribute__((ext_vector_type(4)));

__device__ inline unsigned short f2bf(float f) {
    union { float f; unsigned u; } c; c.f = f;
    return (unsigned short)((c.u + 0x7fffu + ((c.u >> 16) & 1u)) >> 16);
}

// packed 2xf32 -> 2xbf16 (lo = first arg), single VALU op
__device__ inline unsigned cvt_pk_bf16(float lo, float hi) {
    unsigned r;
    asm("v_cvt_pk_bf16_f32 %0, %1, %2" : "=v"(r) : "v"(lo), "v"(hi));
    return r;
}

__device__ inline void gload_lds16(const void* g, void* l) {
    __builtin_amdgcn_global_load_lds(
        (const __attribute__((address_space(1))) unsigned int*)g,
        (__attribute__((address_space(3))) unsigned int*)l, 16, 0, 0);
}

// Workspace layout (float offsets). ~2.4 MB total.
#define WS_ZERO   0             // 64 (zero page for OOB pointer-select)
#define WS_POOLED 64            // 2048
#define WS_CHA    2112          // 2048
#define WS_FA     4160          // 2048
#define WS_KA     6208          // 128
#define WS_SP     6336          // 288
#define WS_W2T    8192          // 1179648 ushorts

// ===========================================================================
// 1) pool: pure streaming reduce. Block = (b,ci) plane (64KB contiguous).
//    Also zeroes the 64-float zero page (block 0) for conv's OOB selects.
// ===========================================================================
__global__ __launch_bounds__(256, 4) void pool_kernel(const float* __restrict__ x,
                                                      float* __restrict__ pooled,
                                                      float* __restrict__ zeros) {
    if (blockIdx.x == 0 && threadIdx.x < 64) zeros[threadIdx.x] = 0.f;
    const int plane = blockIdx.x;               // 2048
    const float4* p = (const float4*)(x + (size_t)plane * (HH * WW));
    float4 v[16];
    #pragma unroll
    for (int i = 0; i < 16; ++i) v[i] = p[threadIdx.x + 256 * i];
    float s = 0.f;
    #pragma unroll
    for (int i = 0; i < 16; ++i) s += v[i].x + v[i].y + v[i].z + v[i].w;
    #pragma unroll
    for (int off = 32; off > 0; off >>= 1) s += __shfl_down(s, off);
    __shared__ float red[4];
    if ((threadIdx.x & 63) == 0) red[threadIdx.x >> 6] = s;
    __syncthreads();
    if (threadIdx.x == 0)
        pooled[plane] = red[0] + red[1] + red[2] + red[3];   // sum; scaled in attn
}

// ===========================================================================
// 2) attention: trunk + 4 heads from pooled sums. 1 block, 512 thr.
// ===========================================================================
__global__ __launch_bounds__(512) void attn3(
    const float* __restrict__ pooled, const float* __restrict__ prep_w,
    const float* __restrict__ bn_g, const float* __restrict__ bn_b,
    const float* __restrict__ bn_m, const float* __restrict__ bn_v,
    const float* __restrict__ fc_sp_w, const float* __restrict__ fc_sp_b,
    const float* __restrict__ fc_ch_w, const float* __restrict__ fc_ch_b,
    const float* __restrict__ fc_f_w,  const float* __restrict__ fc_f_b,
    const float* __restrict__ fc_k_w,  const float* __restrict__ fc_k_b,
    float* __restrict__ sp, float* __restrict__ cha,
    float* __restrict__ fa, float* __restrict__ ka) {
    __shared__ float pooled_s[NB * CI];
    __shared__ float att_s[NB * CA];
    const int tid = threadIdx.x;
    const float scale = 1.f / (HH * WW);
    #pragma unroll
    for (int i = 0; i < 4; ++i) {
        const int e = tid + 512 * i;
        pooled_s[e] = pooled[e];
    }
    __syncthreads();
    const int b = tid >> 4, a = tid & 15;
    {
        float s = 0.f;
        const float* pv = pooled_s + b * CI;
        #pragma unroll
        for (int c = 0; c < CI; ++c) s += pv[c] * prep_w[a * CI + c];
        s = (s * scale - bn_m[a]) * rsqrtf(bn_v[a] + EPSBN) * bn_g[a] + bn_b[a];
        att_s[b * CA + a] = fmaxf(s, 0.f);
    }
    __syncthreads();
    float av[CA];
    #pragma unroll
    for (int i = 0; i < CA; ++i) av[i] = att_s[b * CA + i];

    const int j = a;
    if (j < 9) {
        float s = fc_sp_b[j];
        #pragma unroll
        for (int i = 0; i < CA; ++i) s += av[i] * fc_sp_w[j * CA + i];
        sp[b * 9 + j] = 1.f / (1.f + expf(-s));
    }
    #pragma unroll
    for (int t = 0; t < 4; ++t) {
        const int c = j * 4 + t;
        float s1 = fc_ch_b[c], s2 = fc_f_b[c];
        #pragma unroll
        for (int i = 0; i < CA; ++i) {
            s1 += av[i] * fc_ch_w[c * CA + i];
            s2 += av[i] * fc_f_w[c * CA + i];
        }
        cha[b * CI + c] = 1.f / (1.f + expf(-s1));
        fa[b * CO + c]  = 1.f / (1.f + expf(-s2));
    }
    if (j == 0) {
        float kv[NK], m = -1e30f;
        #pragma unroll
        for (int k = 0; k < NK; ++k) {
            float s = fc_k_b[k];
            #pragma unroll
            for (int i = 0; i < CA; ++i) s += av[i] * fc_k_w[k * CA + i];
            kv[k] = s; m = fmaxf(m, s);
        }
        float den = 0.f;
        #pragma unroll
        for (int k = 0; k < NK; ++k) { kv[k] = expf(kv[k] - m); den += kv[k]; }
        #pragma unroll
        for (int k = 0; k < NK; ++k) ka[b * NK + k] = kv[k] / den;
    }
}

// ===========================================================================
// 3) folded weights w2t[b][tap][o][i] bf16 (lanes = i: 128B-line writes)
// ===========================================================================
__global__ __launch_bounds__(256) void w2t2(const float* __restrict__ kernels,
                                            const float* __restrict__ sp,
                                            const float* __restrict__ cha,
                                            const float* __restrict__ fa,
                                            const float* __restrict__ ka,
                                            unsigned short* __restrict__ w2t) {
    const int bid = blockIdx.x;              // 32*16
    const int b  = bid >> 4;
    const int o  = (bid & 15) * 4 + (threadIdx.x >> 6);
    const int i  = threadIdx.x & 63;
    float kw[NK][9];
    #pragma unroll
    for (int k = 0; k < NK; ++k) {
        const float* kp = kernels + ((size_t)(k * CO + o) * CI + i) * 9;
        #pragma unroll
        for (int t = 0; t < 9; ++t) kw[k][t] = kp[t];
    }
    float kav[NK];
    #pragma unroll
    for (int k = 0; k < NK; ++k) kav[k] = ka[b * NK + k];
    const float base = cha[b * CI + i] * fa[b * CO + o];
    #pragma unroll
    for (int tap = 0; tap < 9; ++tap) {
        float s = 0.f;
        #pragma unroll
        for (int k = 0; k < NK; ++k) s += kav[k] * kw[k][tap];
        w2t[((size_t)(b * 9 + tap) * CO + o) * CI + i] = f2bf(s * sp[b * 9 + tap] * base);
    }
}

// ===========================================================================
// 4) FUSED conv (mfma_f32_16x16x32_bf16), dense-lane x staging with BATCHED
//    loads (zeros-page pointer select -> all 18 loads in flight before use).
//    Block = 64co x 32col x 4row, 256 thr / 4 waves (cohalf x colh).
//    LDS 51200B = x 26624 (oct-XOR layout, r12-proven) + A dbuf 2 x 12288
//    (phase-pipelined, r13-proven). 3 blocks/CU. setprio(1) around MFMA
//    clusters (T5: phase diversity from 3 co-resident blocks).
// ===========================================================================
#define ABASE 26624
#define ABUFB 12288

__global__ __launch_bounds__(256, 3) void conv_fused(const float* __restrict__ x,
                                                     const unsigned short* __restrict__ w2t,
                                                     const float* __restrict__ zeros,
                                                     float* __restrict__ out) {
    __shared__ __align__(16) unsigned char xs[ABASE + 2 * ABUFB];   // 51200
    const int tid  = threadIdx.x;
    const int lane = tid & 63;
    const int wv   = tid >> 6;
    const int orig = blockIdx.x;
    const int bid  = (orig & 7) * 512 + (orig >> 3);    // XCD swizzle (4096 = 8*512)
    const int b    = bid >> 7;
    const int rem  = bid & 127;
    const int colg = rem & 3;
    const int hg   = rem >> 2;
    const int h0 = hg * 4;
    const int w0 = colg * 32;

    const unsigned short* w2base = w2t + (size_t)b * 36864;

    // A chunk stager: chunk c = (ks = c/3, v = c%3) -> buf (c&1).
    auto stageA = [&](int c) {
        const int ks = c / 3, v = c - ks * 3;
        unsigned char* abuf = xs + ABASE + (c & 1) * ABUFB;
        for (int ch = wv; ch < 12; ch += 4) {
            const int u  = ch >> 2;
            const int q  = ch & 3;
            const unsigned short* g = w2base + (size_t)(u * 3 + v) * 4096
                                    + lane * 64 + ks * 32 + q * 8;
            gload_lds16(g, abuf + (ch << 10));
        }
    };

    // ---- x-stage, dense-lane mapping, BATCHED: all 18 loads issued before
    //      any use. OOB -> zeros-page pointer select (branchless).
    const int qlane = lane & 3;
    const int g     = lane >> 2;
    float4 La[9], Lb[9];
    #pragma unroll
    for (int it = 0; it < 9; ++it) {
        const int base = (wv * 9 + it) * 16;
        const int blk  = base >> 5;              // row*3 + iq
        const int row  = blk / 3;
        const int iq   = blk - row * 3;
        const int cip  = (base & 31) + g;        // 16 consecutive ci-pairs
        const int hh   = h0 - 1 + row;
        const int cg   = w0 - 8 + iq * 16 + qlane * 4;
        const bool ok  = ((unsigned)hh < (unsigned)HH) && ((unsigned)cg <= 124u);
        const float* p0 = x + ((size_t)(b * CI + 2 * cip) * HH + hh) * WW + cg;
        const float* pa = ok ? p0 : zeros;
        const float* pb = ok ? (p0 + HH * WW) : zeros;
        La[it] = *(const float4*)pa;
        Lb[it] = *(const float4*)pb;
    }
    // A chunk 0 in flight while we convert/write x
    stageA(0);

    #pragma unroll
    for (int it = 0; it < 9; ++it) {
        const int base = (wv * 9 + it) * 16;
        const int blk  = base >> 5;
        const int row  = blk / 3;
        const int iq   = blk - row * 3;
        const int cip  = (base & 31) + g;
        unsigned char* rbase = xs + row * 4352;
        const int oct = cip >> 2, lo = (cip & 3) * 4;
        const float av[4] = {La[it].x, La[it].y, La[it].z, La[it].w};
        const float cv[4] = {Lb[it].x, Lb[it].y, Lb[it].z, Lb[it].w};
        #pragma unroll
        for (int e = 0; e < 4; ++e) {
            const int cl_ = iq * 16 + qlane * 4 + e - 7;
            if ((unsigned)cl_ < 34u) {
                *(unsigned*)(rbase + cl_ * 128 + ((oct ^ (cl_ & 7)) << 4) + lo) =
                    cvt_pk_bf16(av[e], cv[e]);
            }
        }
    }
    __syncthreads();

    const int cl = lane & 15;        // pixel col in 16 / o in 16
    const int kq = lane >> 4;        // k-quarter within ks-half (8 ci)
    const int cohalf = wv & 1;
    const int colh   = wv >> 1;      // 0..1

    f32x4 acc[2][4];
    #pragma unroll
    for (int og = 0; og < 2; ++og)
        #pragma unroll
        for (int t = 0; t < 4; ++t)
            #pragma unroll
            for (int e = 0; e < 4; ++e) acc[og][t][e] = 0.f;

    const int lcol0 = colh * 16 + cl;
    const int aoff  = kq * 1024 + (cohalf * 32 + cl) * 16;

    // ---- 6 phases: compute chunk c while chunk c+1 streams in
    #pragma unroll
    for (int c = 0; c < 6; ++c) {
        const int ks = c / 3, v = c - ks * 3;
        if (c < 5) stageA(c + 1);
        const unsigned char* abuf = xs + ABASE + (c & 1) * ABUFB;
        const int lcol = lcol0 + v;
        const int sw = ((ks << 2) + kq) ^ (lcol & 7);
        const unsigned char* bp = xs + (((lcol << 3) + sw) << 4);
        bf16x8 Bf[6];
        #pragma unroll
        for (int r = 0; r < 6; ++r) Bf[r] = *(const bf16x8*)(bp + r * 4352);
        __builtin_amdgcn_s_setprio(1);
        #pragma unroll
        for (int u = 0; u < 3; ++u) {
            const unsigned char* ap = abuf + u * 4096 + aoff;
            const bf16x8 A0 = *(const bf16x8*)(ap);
            const bf16x8 A1 = *(const bf16x8*)(ap + 256);     // og=1: +16 o
            #pragma unroll
            for (int t = 0; t < 4; ++t)
                acc[0][t] = __builtin_amdgcn_mfma_f32_16x16x32_bf16(A0, Bf[t + u], acc[0][t], 0, 0, 0);
            #pragma unroll
            for (int t = 0; t < 4; ++t)
                acc[1][t] = __builtin_amdgcn_mfma_f32_16x16x32_bf16(A1, Bf[t + u], acc[1][t], 0, 0, 0);
        }
        __builtin_amdgcn_s_setprio(0);
        if (c < 5) __syncthreads();
    }

    // ---- epilogue: o = cohalf*32 + og*16 + kq*4 + rg, col = w0 + colh*16 + cl
    #pragma unroll
    for (int og = 0; og < 2; ++og)
        #pragma unroll
        for (int t = 0; t < 4; ++t) {
            float* op = out + ((size_t)(b * CO + cohalf * 32 + og * 16 + kq * 4) * HH + h0 + t) * WW
                      + w0 + colh * 16 + cl;
            #pragma unroll
            for (int rg = 0; rg < 4; ++rg)
                op[(size_t)rg * (HH * WW)] = acc[og][t][rg];
        }
}

// ===========================================================================
extern "C" void kernel_launch(void* const* d_in, const int* in_sizes, int n_in,
                              void* d_out, int out_size, void* d_ws, size_t ws_size,
                              hipStream_t stream) {
    const float* x        = (const float*)d_in[0];
    const float* prep_w   = (const float*)d_in[1];
    const float* bn_g     = (const float*)d_in[2];
    const float* bn_b     = (const float*)d_in[3];
    const float* bn_m     = (const float*)d_in[4];
    const float* bn_v     = (const float*)d_in[5];
    const float* fc_sp_w  = (const float*)d_in[6];
    const float* fc_sp_b  = (const float*)d_in[7];
    const float* fc_ch_w  = (const float*)d_in[8];
    const float* fc_ch_b  = (const float*)d_in[9];
    const float* fc_f_w   = (const float*)d_in[10];
    const float* fc_f_b   = (const float*)d_in[11];
    const float* fc_k_w   = (const float*)d_in[12];
    const float* fc_k_b   = (const float*)d_in[13];
    const float* kernels  = (const float*)d_in[14];
    float* out = (float*)d_out;
    float* ws  = (float*)d_ws;

    float* zeros  = ws + WS_ZERO;
    float* pooled = ws + WS_POOLED;
    float* cha    = ws + WS_CHA;
    float* fa     = ws + WS_FA;
    float* ka     = ws + WS_KA;
    float* sp     = ws + WS_SP;
    unsigned short* w2t = (unsigned short*)(ws + WS_W2T);

    pool_kernel<<<NB * CI, 256, 0, stream>>>(x, pooled, zeros);
    attn3<<<1, 512, 0, stream>>>(pooled, prep_w, bn_g, bn_b, bn_m, bn_v,
                                 fc_sp_w, fc_sp_b, fc_ch_w, fc_ch_b,
                                 fc_f_w, fc_f_b, fc_k_w, fc_k_b,
                                 sp, cha, fa, ka);
    w2t2<<<NB * 16, 256, 0, stream>>>(kernels, sp, cha, fa, ka, w2t);
    conv_fused<<<4096, 256, 0, stream>>>(x, w2t, zeros, out);
}